// Round 14
// baseline (104.010 us; speedup 1.0000x reference)
//
#include <hip/hip_runtime.h>
#include <math.h>

namespace {

constexpr int B = 2048;
constexpr int C = 20000;
constexpr int D = 512;
constexpr int LMAX = 8;

constexpr int BMt = 128;                     // GEMM block rows
constexpr int BNt = 256;                     // GEMM block cols
constexpr int NROWT = B / BMt;               // 16 row tiles
constexpr int NPAN  = (C + BNt - 1) / BNt;   // 79 col panels (last: 32 valid of 256)
constexpr int KST   = D / 64;                // 8 K-steps
constexpr int SLOTS_A = BMt * 4;             // 512  16B-slots per (tile,kstep)
constexpr int SLOTS_B = BNt * 4;             // 1024
constexpr int NWG   = NROWT * NPAN;          // 1264 (divisible by 8 XCDs)

constexpr float S_SCALE = 30.0f;
constexpr float COS_M = 0.87758256189037271f;   // cos(0.5)
constexpr float SIN_M = 0.47942553860420301f;   // sin(0.5)
constexpr float TH    = -0.87758256189037271f;  // cos(pi - 0.5)
constexpr float MM    = 0.23971276930210156f;   // sin(pi - 0.5) * 0.5
constexpr float MFIX  = 30.0f;                  // fixed softmax shift: |logits| <= 30

typedef float f32x16 __attribute__((ext_vector_type(16)));

__device__ __forceinline__ void mfma_fp8_t(f32x16& acc, unsigned long long bfrag,
                                           unsigned long long afrag) {
    // transposed: builtin(A=bfrag, B=afrag) -> D cols (lane&31) = logit ROWS
    acc = __builtin_amdgcn_mfma_f32_32x32x16_fp8_fp8((long)bfrag, (long)afrag, acc, 0, 0, 0);
}

// 8 fp32 -> 8 fp8 e4m3 bytes (hardware RNE pack), element j = byte j
__device__ __forceinline__ unsigned long long pack8_fp8(const float* xs, float sc) {
    int d0 = __builtin_amdgcn_cvt_pk_fp8_f32(xs[0] * sc, xs[1] * sc, 0, false);
    d0 = __builtin_amdgcn_cvt_pk_fp8_f32(xs[2] * sc, xs[3] * sc, d0, true);
    int d1 = __builtin_amdgcn_cvt_pk_fp8_f32(xs[4] * sc, xs[5] * sc, 0, false);
    d1 = __builtin_amdgcn_cvt_pk_fp8_f32(xs[6] * sc, xs[7] * sc, d1, true);
    return (unsigned long long)(unsigned)d0 | ((unsigned long long)(unsigned)d1 << 32);
}

__device__ __forceinline__ float wave_sum(float v) {
    #pragma unroll
    for (int off = 1; off < 64; off <<= 1) v += __shfl_xor(v, off, 64);
    return v;
}

// one wave per row: norm + inverse norm over D=512 (coalesced float4 reads)
__global__ void norm_kernel(const float* __restrict__ x, float* __restrict__ nrm_out,
                            float* __restrict__ inv_out, int rows) {
    const int wave = threadIdx.x >> 6, lane = threadIdx.x & 63;
    const int row = blockIdx.x * 4 + wave;
    if (row >= rows) return;
    const float4* p = reinterpret_cast<const float4*>(x + (size_t)row * D);
    const float4 a = p[lane * 2 + 0];
    const float4 b = p[lane * 2 + 1];
    float s = a.x*a.x + a.y*a.y + a.z*a.z + a.w*a.w
            + b.x*b.x + b.y*b.y + b.z*b.z + b.w*b.w;
    s = wave_sum(s);
    if (lane == 0) {
        const float nrm = sqrtf(s);
        nrm_out[row] = nrm;
        inv_out[row] = 1.0f / fmaxf(nrm, 1e-8f);
    }
}

// Pack f -> fp8 e4m3 panels, pre-normalized (GEMM emits cosine directly).
// grid (NROWT, KST). Slot u = q2*64 + l, q2 = m_frag*2 + k32; slot.x/.y = k16
// pair: half h elems j: row = m_frag*32+(l&31), k = k32*32 + h*16 + (l>>5)*8 + j.
__global__ void pack_a_kernel(const float* __restrict__ f, const float* __restrict__ finv,
                              ulonglong2* __restrict__ Ap) {
    const int bx = blockIdx.x, s = blockIdx.y;
    const int t = threadIdx.x;
    ulonglong2* blk = Ap + (size_t)(bx * KST + s) * SLOTS_A;
    #pragma unroll
    for (int i = 0; i < 2; ++i) {
        const int v = i * 256 + t;           // slot 0..511
        const int q2 = v >> 6, l = v & 63;
        const int mfr = q2 >> 1, k32 = q2 & 1;
        const int lrow = mfr * 32 + (l & 31);
        const int row = bx * BMt + lrow;
        const int kb = s * 64 + k32 * 32 + ((l >> 5) << 3);
        const float sc = finv[row];
        float xs[8];
        *reinterpret_cast<float4*>(&xs[0]) = *reinterpret_cast<const float4*>(&f[(size_t)row * D + kb]);
        *reinterpret_cast<float4*>(&xs[4]) = *reinterpret_cast<const float4*>(&f[(size_t)row * D + kb + 4]);
        const unsigned long long lo = pack8_fp8(xs, sc);
        *reinterpret_cast<float4*>(&xs[0]) = *reinterpret_cast<const float4*>(&f[(size_t)row * D + kb + 16]);
        *reinterpret_cast<float4*>(&xs[4]) = *reinterpret_cast<const float4*>(&f[(size_t)row * D + kb + 20]);
        const unsigned long long hi = pack8_fp8(xs, sc);
        blk[v] = make_ulonglong2(lo, hi);
    }
}

// Pack W columns -> fp8 256-col panels; zero-fill cols >= C. grid (NPAN, KST).
__global__ void pack_b_kernel(const float* __restrict__ wsrc, const float* __restrict__ winv,
                              ulonglong2* __restrict__ Bp) {
    const int pan = blockIdx.x, s = blockIdx.y;
    const int t = threadIdx.x;
    ulonglong2* blk = Bp + (size_t)(pan * KST + s) * SLOTS_B;
    #pragma unroll
    for (int i = 0; i < 4; ++i) {
        const int v = i * 256 + t;           // slot 0..1023
        const int q2 = v >> 6, l = v & 63;
        const int mfr = q2 >> 1, k32 = q2 & 1;
        const int lcol = mfr * 32 + (l & 31);
        const int col = pan * BNt + lcol;
        ulonglong2 slot = make_ulonglong2(0ull, 0ull);
        if (col < C) {
            const int kb = s * 64 + k32 * 32 + ((l >> 5) << 3);
            const float sc = winv[col];
            float xs[8];
            *reinterpret_cast<float4*>(&xs[0]) = *reinterpret_cast<const float4*>(&wsrc[(size_t)col * D + kb]);
            *reinterpret_cast<float4*>(&xs[4]) = *reinterpret_cast<const float4*>(&wsrc[(size_t)col * D + kb + 4]);
            slot.x = pack8_fp8(xs, sc);
            *reinterpret_cast<float4*>(&xs[0]) = *reinterpret_cast<const float4*>(&wsrc[(size_t)col * D + kb + 16]);
            *reinterpret_cast<float4*>(&xs[4]) = *reinterpret_cast<const float4*>(&wsrc[(size_t)col * D + kb + 20]);
            slot.y = pack8_fp8(xs, sc);
        }
        blk[v] = slot;
    }
}

// FP8 MFMA GEMM, 128x256 block tile, 4 waves each 64x128 (2 m-frags x 4 n-frags:
// 32 MFMA per 12 fragment loads per k-step). Fragments global->VGPR, explicit
// 2-deep pipeline, no LDS staging/barriers. Transposed accumulate: lane&31 owns
// one logit ROW. pZ[row][panel] = sum_cols exp(30*cos - 30).
__global__ __launch_bounds__(256, 2) void
gemm_mfma_kernel(const ulonglong2* __restrict__ Ap, const ulonglong2* __restrict__ Bp,
                 float* __restrict__ pZ)
{
    __shared__ float sRed[BMt][2];
    const int wgid = blockIdx.x;
    const int swz = (wgid & 7) * (NWG / 8) + (wgid >> 3);   // bijective (NWG%8==0)
    const int bx = swz & 15;          // row tile (16)
    const int by = swz >> 4;          // panel (0..78)
    const int tid  = threadIdx.x;
    const int lane = tid & 63;
    const int half = lane >> 5, l31 = lane & 31;
    const int w    = tid >> 6;
    const int wm   = w >> 1;          // 0..1: rows wm*64
    const int wnn  = w & 1;           // 0..1: cols wnn*128

    const ulonglong2* Aw = Ap + (size_t)bx * KST * SLOTS_A + (wm * 4) * 64 + lane;
    const ulonglong2* Bw = Bp + (size_t)by * KST * SLOTS_B + (wnn * 8) * 64 + lane;

    f32x16 am0n0, am0n1, am0n2, am0n3, am1n0, am1n1, am1n2, am1n3;
    #pragma unroll
    for (int i = 0; i < 16; ++i) {
        am0n0[i]=0.f; am0n1[i]=0.f; am0n2[i]=0.f; am0n3[i]=0.f;
        am1n0[i]=0.f; am1n1[i]=0.f; am1n2[i]=0.f; am1n3[i]=0.f;
    }

    // cur fragments: a[mi][k32] (4), b[nj][k32] (8)
    ulonglong2 ca00 = Aw[0],   ca01 = Aw[64],   ca10 = Aw[128],  ca11 = Aw[192];
    ulonglong2 cb00 = Bw[0],   cb01 = Bw[64],   cb10 = Bw[128],  cb11 = Bw[192];
    ulonglong2 cb20 = Bw[256], cb21 = Bw[320],  cb30 = Bw[384],  cb31 = Bw[448];

    #pragma unroll
    for (int s = 0; s < KST; ++s) {
        ulonglong2 na00, na01, na10, na11;
        ulonglong2 nb00, nb01, nb10, nb11, nb20, nb21, nb30, nb31;
        if (s + 1 < KST) {                       // issue next-step loads FIRST
            const ulonglong2* As = Aw + (s + 1) * SLOTS_A;
            const ulonglong2* Bs = Bw + (s + 1) * SLOTS_B;
            na00 = As[0];   na01 = As[64];  na10 = As[128]; na11 = As[192];
            nb00 = Bs[0];   nb01 = Bs[64];  nb10 = Bs[128]; nb11 = Bs[192];
            nb20 = Bs[256]; nb21 = Bs[320]; nb30 = Bs[384]; nb31 = Bs[448];
        }
        // 32 MFMAs: (k32,h) x mi(2) x nj(4)
        mfma_fp8_t(am0n0, cb00.x, ca00.x); mfma_fp8_t(am1n0, cb00.x, ca10.x);
        mfma_fp8_t(am0n1, cb10.x, ca00.x); mfma_fp8_t(am1n1, cb10.x, ca10.x);
        mfma_fp8_t(am0n2, cb20.x, ca00.x); mfma_fp8_t(am1n2, cb20.x, ca10.x);
        mfma_fp8_t(am0n3, cb30.x, ca00.x); mfma_fp8_t(am1n3, cb30.x, ca10.x);
        mfma_fp8_t(am0n0, cb00.y, ca00.y); mfma_fp8_t(am1n0, cb00.y, ca10.y);
        mfma_fp8_t(am0n1, cb10.y, ca00.y); mfma_fp8_t(am1n1, cb10.y, ca10.y);
        mfma_fp8_t(am0n2, cb20.y, ca00.y); mfma_fp8_t(am1n2, cb20.y, ca10.y);
        mfma_fp8_t(am0n3, cb30.y, ca00.y); mfma_fp8_t(am1n3, cb30.y, ca10.y);
        mfma_fp8_t(am0n0, cb01.x, ca01.x); mfma_fp8_t(am1n0, cb01.x, ca11.x);
        mfma_fp8_t(am0n1, cb11.x, ca01.x); mfma_fp8_t(am1n1, cb11.x, ca11.x);
        mfma_fp8_t(am0n2, cb21.x, ca01.x); mfma_fp8_t(am1n2, cb21.x, ca11.x);
        mfma_fp8_t(am0n3, cb31.x, ca01.x); mfma_fp8_t(am1n3, cb31.x, ca11.x);
        mfma_fp8_t(am0n0, cb01.y, ca01.y); mfma_fp8_t(am1n0, cb01.y, ca11.y);
        mfma_fp8_t(am0n1, cb11.y, ca01.y); mfma_fp8_t(am1n1, cb11.y, ca11.y);
        mfma_fp8_t(am0n2, cb21.y, ca01.y); mfma_fp8_t(am1n2, cb21.y, ca11.y);
        mfma_fp8_t(am0n3, cb31.y, ca01.y); mfma_fp8_t(am1n3, cb31.y, ca11.y);
        if (s + 1 < KST) {
            ca00 = na00; ca01 = na01; ca10 = na10; ca11 = na11;
            cb00 = nb00; cb01 = nb01; cb10 = nb10; cb11 = nb11;
            cb20 = nb20; cb21 = nb21; cb30 = nb30; cb31 = nb31;
        }
    }

    // ---- epilogue: per-lane row partials, single cross-lane step ----
    float zA = 0.0f;   // row = wm*64 + l31
    float zB = 0.0f;   // row = wm*64 + 32 + l31
    const int cbase = by * BNt + wnn * 128 + 4 * half;
#define EPI_NJ(ACC0, ACC1, NJ)                                                   \
    {                                                                            \
        _Pragma("unroll")                                                        \
        for (int r = 0; r < 16; ++r) {                                           \
            const int cb = cbase + (NJ) * 32 + (r & 3) + 8 * (r >> 2);           \
            zA += (cb < C) ? __expf(fmaf((ACC0)[r], S_SCALE, -MFIX)) : 0.0f;     \
            zB += (cb < C) ? __expf(fmaf((ACC1)[r], S_SCALE, -MFIX)) : 0.0f;     \
        }                                                                        \
    }
    EPI_NJ(am0n0, am1n0, 0)
    EPI_NJ(am0n1, am1n1, 1)
    EPI_NJ(am0n2, am1n2, 2)
    EPI_NJ(am0n3, am1n3, 3)
#undef EPI_NJ
    zA += __shfl_xor(zA, 32, 64);    // combine the two 4-col half-groups
    zB += __shfl_xor(zB, 32, 64);
    if (half == 0) {
        sRed[wm * 64 + l31][wnn]      = zA;
        sRed[wm * 64 + 32 + l31][wnn] = zB;
    }
    __syncthreads();
    if (tid < BMt) {
        pZ[(size_t)(bx * BMt + tid) * NPAN + by] = sRed[tid][0] + sRed[tid][1];
    }
}

// One wave per row: sum NPAN partials (fixed shift M=30), exact fp32 target
// logits + ArcFace margin, correct Z, emit per-row loss.
__global__ void finalize_kernel(const float* __restrict__ f, const float* __restrict__ w,
                                const float* __restrict__ fn, const float* __restrict__ wn,
                                const int* __restrict__ pinds, const int* __restrict__ lengths,
                                const float* __restrict__ pZ, float* __restrict__ loss)
{
    const int b = blockIdx.x;
    const int lane = threadIdx.x;

    float Zp = 0.0f;
    for (int p = lane; p < NPAN; p += 64) Zp += pZ[(size_t)b * NPAN + p];
    Zp = wave_sum(Zp);

    const float4* fp = reinterpret_cast<const float4*>(f + (size_t)b * D);
    const float4 a0 = fp[lane * 2 + 0];
    const float4 a1 = fp[lane * 2 + 1];
    const float fnb = fn[b];
    const int len = lengths[b];

    float opl[LMAX], ops[LMAX];
    int cs[LMAX];
    #pragma unroll
    for (int j = 0; j < LMAX; ++j) {
        const int c = pinds[(size_t)b * LMAX + j];
        cs[j] = c;
        const float4* wp = reinterpret_cast<const float4*>(w + (size_t)c * D);
        const float4 w0 = wp[lane * 2 + 0];
        const float4 w1 = wp[lane * 2 + 1];
        float d = a0.x*w0.x + a0.y*w0.y + a0.z*w0.z + a0.w*w0.w
                + a1.x*w1.x + a1.y*w1.y + a1.z*w1.z + a1.w*w1.w;
        d = wave_sum(d);
        const float cosv = d / fmaxf(fnb * wn[c], 1e-8f);
        const float sine = sqrtf(fminf(fmaxf(1.0f - cosv * cosv, 0.0f), 1.0f));
        float phi = cosv * COS_M - sine * SIN_M;
        phi = (cosv > TH) ? phi : (cosv - MM);
        opl[j] = S_SCALE * cosv;
        ops[j] = S_SCALE * phi;
    }

    // correct Z for unique positive classes (margin applied), then ragged CE
    float Zc = Zp;
    for (int j = 0; j < len; ++j) {
        bool dup = false;
        for (int jj = 0; jj < j; ++jj) dup = dup || (cs[jj] == cs[j]);
        if (!dup) Zc += expf(ops[j] - MFIX) - expf(opl[j] - MFIX);
    }
    const float lZ = logf(Zc);
    float acc = 0.0f;
    for (int j = 0; j < len; ++j) acc += (MFIX + lZ - ops[j]);
    const float Lf = (float)len;
    if (lane == 0) loss[b] = acc / (Lf * Lf);
}

__global__ void reduce_kernel(const float* __restrict__ loss, float* __restrict__ out) {
    __shared__ float sdata[256];
    const int t = threadIdx.x;
    float s = 0.0f;
    for (int i = t; i < B; i += 256) s += loss[i];
    sdata[t] = s;
    __syncthreads();
    for (int off = 128; off > 0; off >>= 1) {
        if (t < off) sdata[t] += sdata[t + off];
        __syncthreads();
    }
    if (t == 0) out[0] = sdata[0] * (1.0f / (float)B);
}

} // anonymous namespace

extern "C" void kernel_launch(void* const* d_in, const int* in_sizes, int n_in,
                              void* d_out, int out_size, void* d_ws, size_t ws_size,
                              hipStream_t stream) {
    const float* f   = (const float*)d_in[0];
    // d_in[1] = labels [B,C] — not needed (reconstructed from pinds/lengths)
    const float* w   = (const float*)d_in[2];
    const int* pinds = (const int*)d_in[3];
    const int* lens  = (const int*)d_in[4];
    float* out = (float*)d_out;

    char* ws = (char*)d_ws;
    size_t off = 0;
    auto alloc = [&](size_t bytes) { void* p = ws + off; off = (off + bytes + 255) & ~(size_t)255; return p; };

    float* wn   = (float*)alloc(C * 4);
    float* winv = (float*)alloc(C * 4);
    float* fn   = (float*)alloc(B * 4);
    float* finv = (float*)alloc(B * 4);
    float* pZ   = (float*)alloc((size_t)B * NPAN * 4);
    float* loss = (float*)alloc(B * 4);
    ulonglong2* Ap = (ulonglong2*)alloc((size_t)NROWT * KST * SLOTS_A * 16);
    ulonglong2* Bp = (ulonglong2*)alloc((size_t)NPAN  * KST * SLOTS_B * 16);

    norm_kernel<<<dim3(B / 4), 256, 0, stream>>>(f, fn, finv, B);
    norm_kernel<<<dim3(C / 4), 256, 0, stream>>>(w, wn, winv, C);
    pack_a_kernel<<<dim3(NROWT, KST), 256, 0, stream>>>(f, finv, Ap);
    pack_b_kernel<<<dim3(NPAN, KST), 256, 0, stream>>>(w, winv, Bp);
    gemm_mfma_kernel<<<dim3(NWG), 256, 0, stream>>>(Ap, Bp, pZ);
    finalize_kernel<<<dim3(B), 64, 0, stream>>>(f, w, fn, wn, pinds, lens, pZ, loss);
    reduce_kernel<<<dim3(1), 256, 0, stream>>>(loss, out);
}

// Round 15
// 83.786 us; speedup vs baseline: 1.2414x; 1.2414x over previous
//
#include <hip/hip_runtime.h>
#include <math.h>

namespace {

constexpr int B = 2048;
constexpr int C = 20000;
constexpr int D = 512;
constexpr int LMAX = 8;

constexpr int BMt = 128, BNt = 128;          // GEMM block tile
constexpr int NROWT = B / BMt;               // 16 row tiles
constexpr int NPAN  = (C + BNt - 1) / BNt;   // 157 col panels (last: 32 valid)
constexpr int KST   = D / 64;                // 8 K-steps
constexpr int SLOTS = 512;                   // 16B slots per (tile,kstep)
constexpr int NWG   = NROWT * NPAN;          // 2512 (divisible by 8 XCDs)
constexpr int NPACK_A = NROWT * KST;         // 128 pack blocks for A
constexpr int NPACK_B = NPAN * KST;          // 1256 pack blocks for B

constexpr float S_SCALE = 30.0f;
constexpr float COS_M = 0.87758256189037271f;   // cos(0.5)
constexpr float SIN_M = 0.47942553860420301f;   // sin(0.5)
constexpr float TH    = -0.87758256189037271f;  // cos(pi - 0.5)
constexpr float MM    = 0.23971276930210156f;   // sin(pi - 0.5) * 0.5
constexpr float MFIX  = 30.0f;                  // fixed softmax shift: |logits| <= 30

typedef float f32x16 __attribute__((ext_vector_type(16)));

__device__ __forceinline__ void mfma_fp8_t(f32x16& acc, unsigned long long bfrag,
                                           unsigned long long afrag) {
    // transposed: builtin(A=bfrag, B=afrag) -> D cols (lane&31) = logit ROWS
    acc = __builtin_amdgcn_mfma_f32_32x32x16_fp8_fp8((long)bfrag, (long)afrag, acc, 0, 0, 0);
}

// 8 fp32 -> 8 fp8 e4m3 bytes (hardware RNE pack), element j = byte j
__device__ __forceinline__ unsigned long long pack8_fp8(const float* xs, float sc) {
    int d0 = __builtin_amdgcn_cvt_pk_fp8_f32(xs[0] * sc, xs[1] * sc, 0, false);
    d0 = __builtin_amdgcn_cvt_pk_fp8_f32(xs[2] * sc, xs[3] * sc, d0, true);
    int d1 = __builtin_amdgcn_cvt_pk_fp8_f32(xs[4] * sc, xs[5] * sc, 0, false);
    d1 = __builtin_amdgcn_cvt_pk_fp8_f32(xs[6] * sc, xs[7] * sc, d1, true);
    return (unsigned long long)(unsigned)d0 | ((unsigned long long)(unsigned)d1 << 32);
}

__device__ __forceinline__ float wave_sum(float v) {
    #pragma unroll
    for (int off = 1; off < 64; off <<= 1) v += __shfl_xor(v, off, 64);
    return v;
}

// Merged norm: one wave per row over BOTH f (rows 0..B) and w (rows B..B+C).
// Coalesced float4 reads; writes nrm and 1/nrm.
__global__ void norm_kernel(const float* __restrict__ f, const float* __restrict__ w,
                            float* __restrict__ fn, float* __restrict__ finv,
                            float* __restrict__ wn, float* __restrict__ winv) {
    const int wave = threadIdx.x >> 6, lane = threadIdx.x & 63;
    const int r = blockIdx.x * 4 + wave;
    const float* x;
    float *no, *io;
    int row;
    if (r < B) { x = f; row = r; no = fn; io = finv; }
    else       { x = w; row = r - B; no = wn; io = winv; if (row >= C) return; }
    const float4* p = reinterpret_cast<const float4*>(x + (size_t)row * D);
    const float4 a = p[lane * 2 + 0];
    const float4 b = p[lane * 2 + 1];
    float s = a.x*a.x + a.y*a.y + a.z*a.z + a.w*a.w
            + b.x*b.x + b.y*b.y + b.z*b.z + b.w*b.w;
    s = wave_sum(s);
    if (lane == 0) {
        const float nrm = sqrtf(s);
        no[row] = nrm;
        io[row] = 1.0f / fmaxf(nrm, 1e-8f);
    }
}

// Merged pack: blocks [0,128) pack A tiles, [128,1384) pack B panels.
// Pre-normalized fp8 e4m3. Slot u = q2*64 + l, q2 = m_frag*2 + k32; slot.x/.y
// = k16 pair: half h elems j: row = m_frag*32+(l&31), k = k32*32+h*16+(l>>5)*8+j.
__global__ void pack_kernel(const float* __restrict__ f, const float* __restrict__ finv,
                            const float* __restrict__ w, const float* __restrict__ winv,
                            ulonglong2* __restrict__ Ap, ulonglong2* __restrict__ Bp) {
    const int id = blockIdx.x;
    const bool isA = id < NPACK_A;
    const int bid = isA ? id : id - NPACK_A;
    const int tile = bid >> 3, s = bid & 7;
    const int rbase = tile * 128;
    const float* src = isA ? f : w;
    const float* inv = isA ? finv : winv;
    ulonglong2* blk = (isA ? Ap : Bp) + (size_t)bid * SLOTS;
    const int t = threadIdx.x;
    #pragma unroll
    for (int i = 0; i < 2; ++i) {
        const int v = i * 256 + t;           // slot 0..511
        const int q2 = v >> 6, l = v & 63;
        const int mfr = q2 >> 1, k32 = q2 & 1;
        const int row = rbase + mfr * 32 + (l & 31);
        ulonglong2 slot = make_ulonglong2(0ull, 0ull);
        if (isA || row < C) {
            const int kb = s * 64 + k32 * 32 + ((l >> 5) << 3);
            const float sc = inv[row];
            float xs[8];
            *reinterpret_cast<float4*>(&xs[0]) = *reinterpret_cast<const float4*>(&src[(size_t)row * D + kb]);
            *reinterpret_cast<float4*>(&xs[4]) = *reinterpret_cast<const float4*>(&src[(size_t)row * D + kb + 4]);
            slot.x = pack8_fp8(xs, sc);
            *reinterpret_cast<float4*>(&xs[0]) = *reinterpret_cast<const float4*>(&src[(size_t)row * D + kb + 16]);
            *reinterpret_cast<float4*>(&xs[4]) = *reinterpret_cast<const float4*>(&src[(size_t)row * D + kb + 20]);
            slot.y = pack8_fp8(xs, sc);
        }
        blk[v] = slot;
    }
}

// FP8 MFMA GEMM (R12-proven): 128x128 tile, 4 waves (2x2) each 64x64.
// Fragments global->VGPR, explicit 2-deep pipeline, no LDS staging/barriers.
// s_setprio(1) around each MFMA cluster (waves are phase-independent here).
// Transposed accumulate: lane&31 owns one logit ROW.
// pZ[row][panel] = sum_cols exp(30*cos - 30).
__global__ __launch_bounds__(256, 3) void
gemm_mfma_kernel(const ulonglong2* __restrict__ Ap, const ulonglong2* __restrict__ Bp,
                 float* __restrict__ pZ)
{
    __shared__ float sRed[BMt][2];
    const int wgid = blockIdx.x;
    const int swz = (wgid & 7) * (NWG / 8) + (wgid >> 3);   // bijective (NWG%8==0)
    const int bx = swz & 15;          // row tile
    const int by = swz >> 4;          // panel
    const int tid  = threadIdx.x;
    const int lane = tid & 63;
    const int half = lane >> 5, l31 = lane & 31;
    const int w    = tid >> 6;
    const int wm   = w >> 1;          // 0..1: rows wm*64
    const int wnn  = w & 1;           // 0..1: cols wnn*64

    const ulonglong2* Aw = Ap + (size_t)bx * KST * SLOTS + (wm * 4) * 64 + lane;
    const ulonglong2* Bw = Bp + (size_t)by * KST * SLOTS + (wnn * 4) * 64 + lane;

    f32x16 accT00, accT01, accT10, accT11;   // cols(lane&31)=logit rows
    #pragma unroll
    for (int i = 0; i < 16; ++i) { accT00[i] = 0.f; accT01[i] = 0.f; accT10[i] = 0.f; accT11[i] = 0.f; }

    // cur fragments: a{mfr,k32}: ca0={m0,k0} ca1={m0,k1} ca2={m1,k0} ca3={m1,k1}
    ulonglong2 ca0 = Aw[0], ca1 = Aw[64], ca2 = Aw[128], ca3 = Aw[192];
    ulonglong2 cb0 = Bw[0], cb1 = Bw[64], cb2 = Bw[128], cb3 = Bw[192];

    #pragma unroll
    for (int s = 0; s < KST; ++s) {
        ulonglong2 na0, na1, na2, na3, nb0, nb1, nb2, nb3;
        if (s + 1 < KST) {                       // issue next-step loads FIRST
            const ulonglong2* As = Aw + (s + 1) * SLOTS;
            const ulonglong2* Bs = Bw + (s + 1) * SLOTS;
            na0 = As[0]; na1 = As[64]; na2 = As[128]; na3 = As[192];
            nb0 = Bs[0]; nb1 = Bs[64]; nb2 = Bs[128]; nb3 = Bs[192];
        }
        __builtin_amdgcn_s_setprio(1);
        // 16 MFMAs on current fragments (k16 = {k32, h->.x/.y})
        mfma_fp8_t(accT00, cb0.x, ca0.x);
        mfma_fp8_t(accT01, cb0.x, ca2.x);
        mfma_fp8_t(accT10, cb2.x, ca0.x);
        mfma_fp8_t(accT11, cb2.x, ca2.x);
        mfma_fp8_t(accT00, cb0.y, ca0.y);
        mfma_fp8_t(accT01, cb0.y, ca2.y);
        mfma_fp8_t(accT10, cb2.y, ca0.y);
        mfma_fp8_t(accT11, cb2.y, ca2.y);
        mfma_fp8_t(accT00, cb1.x, ca1.x);
        mfma_fp8_t(accT01, cb1.x, ca3.x);
        mfma_fp8_t(accT10, cb3.x, ca1.x);
        mfma_fp8_t(accT11, cb3.x, ca3.x);
        mfma_fp8_t(accT00, cb1.y, ca1.y);
        mfma_fp8_t(accT01, cb1.y, ca3.y);
        mfma_fp8_t(accT10, cb3.y, ca1.y);
        mfma_fp8_t(accT11, cb3.y, ca3.y);
        __builtin_amdgcn_s_setprio(0);
        if (s + 1 < KST) {
            ca0 = na0; ca1 = na1; ca2 = na2; ca3 = na3;
            cb0 = nb0; cb1 = nb1; cb2 = nb2; cb3 = nb3;
        }
    }

    // ---- epilogue: per-lane row partials, single cross-lane step ----
    float zA = 0.0f;   // row = wm*64 + l31
    float zB = 0.0f;   // row = wm*64 + 32 + l31
    const int cbase = by * BNt + wnn * 64 + 4 * half;
    #pragma unroll
    for (int r = 0; r < 16; ++r) {
        const int cb = cbase + (r & 3) + 8 * (r >> 2);
        const float eA0 = (cb      < C) ? __expf(fmaf(accT00[r], S_SCALE, -MFIX)) : 0.0f;
        const float eB0 = (cb      < C) ? __expf(fmaf(accT01[r], S_SCALE, -MFIX)) : 0.0f;
        const float eA1 = (cb + 32 < C) ? __expf(fmaf(accT10[r], S_SCALE, -MFIX)) : 0.0f;
        const float eB1 = (cb + 32 < C) ? __expf(fmaf(accT11[r], S_SCALE, -MFIX)) : 0.0f;
        zA += eA0 + eA1;
        zB += eB0 + eB1;
    }
    zA += __shfl_xor(zA, 32, 64);    // combine the two col-halves of each row
    zB += __shfl_xor(zB, 32, 64);
    if (half == 0) {
        sRed[wm * 64 + l31][wnn]      = zA;
        sRed[wm * 64 + 32 + l31][wnn] = zB;
    }
    __syncthreads();
    if (tid < BMt) {
        pZ[(size_t)(bx * BMt + tid) * NPAN + by] = sRed[tid][0] + sRed[tid][1];
    }
}

// One wave per row: sum NPAN partials (fixed shift M=30), exact fp32 target
// logits + ArcFace margin, correct Z, emit per-row loss.
__global__ void finalize_kernel(const float* __restrict__ f, const float* __restrict__ w,
                                const float* __restrict__ fn, const float* __restrict__ wn,
                                const int* __restrict__ pinds, const int* __restrict__ lengths,
                                const float* __restrict__ pZ, float* __restrict__ loss)
{
    const int b = blockIdx.x;
    const int lane = threadIdx.x;

    float Zp = 0.0f;
    for (int p = lane; p < NPAN; p += 64) Zp += pZ[(size_t)b * NPAN + p];
    Zp = wave_sum(Zp);

    const float4* fp = reinterpret_cast<const float4*>(f + (size_t)b * D);
    const float4 a0 = fp[lane * 2 + 0];
    const float4 a1 = fp[lane * 2 + 1];
    const float fnb = fn[b];
    const int len = lengths[b];

    float opl[LMAX], ops[LMAX];
    int cs[LMAX];
    #pragma unroll
    for (int j = 0; j < LMAX; ++j) {
        const int c = pinds[(size_t)b * LMAX + j];
        cs[j] = c;
        const float4* wp = reinterpret_cast<const float4*>(w + (size_t)c * D);
        const float4 w0 = wp[lane * 2 + 0];
        const float4 w1 = wp[lane * 2 + 1];
        float d = a0.x*w0.x + a0.y*w0.y + a0.z*w0.z + a0.w*w0.w
                + a1.x*w1.x + a1.y*w1.y + a1.z*w1.z + a1.w*w1.w;
        d = wave_sum(d);
        const float cosv = d / fmaxf(fnb * wn[c], 1e-8f);
        const float sine = sqrtf(fminf(fmaxf(1.0f - cosv * cosv, 0.0f), 1.0f));
        float phi = cosv * COS_M - sine * SIN_M;
        phi = (cosv > TH) ? phi : (cosv - MM);
        opl[j] = S_SCALE * cosv;
        ops[j] = S_SCALE * phi;
    }

    // correct Z for unique positive classes (margin applied), then ragged CE
    float Zc = Zp;
    for (int j = 0; j < len; ++j) {
        bool dup = false;
        for (int jj = 0; jj < j; ++jj) dup = dup || (cs[jj] == cs[j]);
        if (!dup) Zc += expf(ops[j] - MFIX) - expf(opl[j] - MFIX);
    }
    const float lZ = logf(Zc);
    float acc = 0.0f;
    for (int j = 0; j < len; ++j) acc += (MFIX + lZ - ops[j]);
    const float Lf = (float)len;
    if (lane == 0) loss[b] = acc / (Lf * Lf);
}

__global__ void reduce_kernel(const float* __restrict__ loss, float* __restrict__ out) {
    __shared__ float sdata[256];
    const int t = threadIdx.x;
    float s = 0.0f;
    for (int i = t; i < B; i += 256) s += loss[i];
    sdata[t] = s;
    __syncthreads();
    for (int off = 128; off > 0; off >>= 1) {
        if (t < off) sdata[t] += sdata[t + off];
        __syncthreads();
    }
    if (t == 0) out[0] = sdata[0] * (1.0f / (float)B);
}

} // anonymous namespace

extern "C" void kernel_launch(void* const* d_in, const int* in_sizes, int n_in,
                              void* d_out, int out_size, void* d_ws, size_t ws_size,
                              hipStream_t stream) {
    const float* f   = (const float*)d_in[0];
    // d_in[1] = labels [B,C] — not needed (reconstructed from pinds/lengths)
    const float* w   = (const float*)d_in[2];
    const int* pinds = (const int*)d_in[3];
    const int* lens  = (const int*)d_in[4];
    float* out = (float*)d_out;

    char* ws = (char*)d_ws;
    size_t off = 0;
    auto alloc = [&](size_t bytes) { void* p = ws + off; off = (off + bytes + 255) & ~(size_t)255; return p; };

    float* wn   = (float*)alloc(C * 4);
    float* winv = (float*)alloc(C * 4);
    float* fn   = (float*)alloc(B * 4);
    float* finv = (float*)alloc(B * 4);
    float* pZ   = (float*)alloc((size_t)B * NPAN * 4);
    float* loss = (float*)alloc(B * 4);
    ulonglong2* Ap = (ulonglong2*)alloc((size_t)NROWT * KST * SLOTS * 16);
    ulonglong2* Bp = (ulonglong2*)alloc((size_t)NPAN  * KST * SLOTS * 16);

    norm_kernel<<<dim3((B + C) / 4), 256, 0, stream>>>(f, w, fn, finv, wn, winv);
    pack_kernel<<<dim3(NPACK_A + NPACK_B), 256, 0, stream>>>(f, finv, w, winv, Ap, Bp);
    gemm_mfma_kernel<<<dim3(NWG), 256, 0, stream>>>(Ap, Bp, pZ);
    finalize_kernel<<<dim3(B), 64, 0, stream>>>(f, w, fn, wn, pinds, lens, pZ, loss);
    reduce_kernel<<<dim3(1), 256, 0, stream>>>(loss, out);
}

// Round 16
// 70.675 us; speedup vs baseline: 1.4717x; 1.1855x over previous
//
#include <hip/hip_runtime.h>
#include <math.h>

namespace {

constexpr int B = 2048;
constexpr int C = 20000;
constexpr int D = 512;
constexpr int LMAX = 8;

constexpr int BMt = 128, BNt = 128;          // GEMM block tile
constexpr int NROWT = B / BMt;               // 16 row tiles
constexpr int NPAN  = (C + BNt - 1) / BNt;   // 157 col panels (last: 32 valid)
constexpr int KST   = D / 64;                // 8 K-steps
constexpr int SLOTS = 512;                   // 16B slots per (tile,kstep)
constexpr int NWG   = NROWT * NPAN;          // 2512 (divisible by 8 XCDs)
constexpr int NPACK_A = NROWT * KST;         // 128 pack blocks for A
constexpr int NPACK_B = NPAN * KST;          // 1256 pack blocks for B

constexpr float S_SCALE = 30.0f;
constexpr float COS_M = 0.87758256189037271f;   // cos(0.5)
constexpr float SIN_M = 0.47942553860420301f;   // sin(0.5)
constexpr float TH    = -0.87758256189037271f;  // cos(pi - 0.5)
constexpr float MM    = 0.23971276930210156f;   // sin(pi - 0.5) * 0.5
constexpr float MFIX  = 30.0f;                  // fixed softmax shift: |logits| <= 30

typedef float f32x16 __attribute__((ext_vector_type(16)));

__device__ __forceinline__ void mfma_fp8_t(f32x16& acc, unsigned long long bfrag,
                                           unsigned long long afrag) {
    // transposed: builtin(A=bfrag, B=afrag) -> D cols (lane&31) = logit ROWS
    acc = __builtin_amdgcn_mfma_f32_32x32x16_fp8_fp8((long)bfrag, (long)afrag, acc, 0, 0, 0);
}

// async global->LDS, 16B per lane; LDS dest = uniform base + lane*16 (HW).
__device__ __forceinline__ void gload_lds16(const ulonglong2* gsrc_lane, ulonglong2* lds_base) {
    __builtin_amdgcn_global_load_lds(
        (const __attribute__((address_space(1))) unsigned int*)gsrc_lane,
        (__attribute__((address_space(3))) unsigned int*)lds_base,
        16, 0, 0);
}

// 8 fp32 -> 8 fp8 e4m3 bytes (hardware RNE pack), element j = byte j
__device__ __forceinline__ unsigned long long pack8_fp8(const float* xs, float sc) {
    int d0 = __builtin_amdgcn_cvt_pk_fp8_f32(xs[0] * sc, xs[1] * sc, 0, false);
    d0 = __builtin_amdgcn_cvt_pk_fp8_f32(xs[2] * sc, xs[3] * sc, d0, true);
    int d1 = __builtin_amdgcn_cvt_pk_fp8_f32(xs[4] * sc, xs[5] * sc, 0, false);
    d1 = __builtin_amdgcn_cvt_pk_fp8_f32(xs[6] * sc, xs[7] * sc, d1, true);
    return (unsigned long long)(unsigned)d0 | ((unsigned long long)(unsigned)d1 << 32);
}

__device__ __forceinline__ float wave_sum(float v) {
    #pragma unroll
    for (int off = 1; off < 64; off <<= 1) v += __shfl_xor(v, off, 64);
    return v;
}

// Merged norm: one wave per row over BOTH f (rows 0..B) and w (rows B..B+C).
__global__ void norm_kernel(const float* __restrict__ f, const float* __restrict__ w,
                            float* __restrict__ fn, float* __restrict__ finv,
                            float* __restrict__ wn, float* __restrict__ winv) {
    const int wave = threadIdx.x >> 6, lane = threadIdx.x & 63;
    const int r = blockIdx.x * 4 + wave;
    const float* x;
    float *no, *io;
    int row;
    if (r < B) { x = f; row = r; no = fn; io = finv; }
    else       { x = w; row = r - B; no = wn; io = winv; if (row >= C) return; }
    const float4* p = reinterpret_cast<const float4*>(x + (size_t)row * D);
    const float4 a = p[lane * 2 + 0];
    const float4 b = p[lane * 2 + 1];
    float s = a.x*a.x + a.y*a.y + a.z*a.z + a.w*a.w
            + b.x*b.x + b.y*b.y + b.z*b.z + b.w*b.w;
    s = wave_sum(s);
    if (lane == 0) {
        const float nrm = sqrtf(s);
        no[row] = nrm;
        io[row] = 1.0f / fmaxf(nrm, 1e-8f);
    }
}

// Merged pack: blocks [0,128) pack A tiles, [128,1384) pack B panels.
// Pre-normalized fp8 e4m3. Slot u = q2*64 + l, q2 = m_frag*2 + k32; slot.x/.y
// = k16 pair: half h elems j: row = m_frag*32+(l&31), k = k32*32+h*16+(l>>5)*8+j.
__global__ void pack_kernel(const float* __restrict__ f, const float* __restrict__ finv,
                            const float* __restrict__ w, const float* __restrict__ winv,
                            ulonglong2* __restrict__ Ap, ulonglong2* __restrict__ Bp) {
    const int id = blockIdx.x;
    const bool isA = id < NPACK_A;
    const int bid = isA ? id : id - NPACK_A;
    const int tile = bid >> 3, s = bid & 7;
    const int rbase = tile * 128;
    const float* src = isA ? f : w;
    const float* inv = isA ? finv : winv;
    ulonglong2* blk = (isA ? Ap : Bp) + (size_t)bid * SLOTS;
    const int t = threadIdx.x;
    #pragma unroll
    for (int i = 0; i < 2; ++i) {
        const int v = i * 256 + t;           // slot 0..511
        const int q2 = v >> 6, l = v & 63;
        const int mfr = q2 >> 1, k32 = q2 & 1;
        const int row = rbase + mfr * 32 + (l & 31);
        ulonglong2 slot = make_ulonglong2(0ull, 0ull);
        if (isA || row < C) {
            const int kb = s * 64 + k32 * 32 + ((l >> 5) << 3);
            const float sc = inv[row];
            float xs[8];
            *reinterpret_cast<float4*>(&xs[0]) = *reinterpret_cast<const float4*>(&src[(size_t)row * D + kb]);
            *reinterpret_cast<float4*>(&xs[4]) = *reinterpret_cast<const float4*>(&src[(size_t)row * D + kb + 4]);
            slot.x = pack8_fp8(xs, sc);
            *reinterpret_cast<float4*>(&xs[0]) = *reinterpret_cast<const float4*>(&src[(size_t)row * D + kb + 16]);
            *reinterpret_cast<float4*>(&xs[4]) = *reinterpret_cast<const float4*>(&src[(size_t)row * D + kb + 20]);
            slot.y = pack8_fp8(xs, sc);
        }
        blk[v] = slot;
    }
}

// FP8 MFMA GEMM with LDS double-buffer + counted vmcnt deep pipeline (T3/T4):
// global_load_lds stages each k-step ONCE per block (halves L1 traffic vs
// per-wave direct loads); fragments come from the separate LDS pipe.
// vmcnt is never drained to 0 in the main loop: stage s+2 stays in flight
// while MFMAs consume s. Raw s_barrier (NOT __syncthreads -> no vmcnt(0)).
// Transposed accumulate: lane&31 owns one logit ROW.
// pZ[row][panel] = sum_cols exp(30*cos - 30).
__global__ __launch_bounds__(256, 3) void
gemm_mfma_kernel(const ulonglong2* __restrict__ Ap, const ulonglong2* __restrict__ Bp,
                 float* __restrict__ pZ)
{
    __shared__ ulonglong2 sBuf[2][1024];   // [buf][A:0..511 | B:512..1023] = 32KB
    __shared__ float sRed[BMt][2];
    const int wgid = blockIdx.x;
    const int swz = (wgid & 7) * (NWG / 8) + (wgid >> 3);   // bijective (NWG%8==0)
    const int bx = swz & 15;          // row tile
    const int by = swz >> 4;          // panel
    const int tid  = threadIdx.x;
    const int lane = tid & 63;
    const int half = lane >> 5, l31 = lane & 31;
    const int w    = tid >> 6;
    const int wm   = w >> 1;          // 0..1: rows wm*64
    const int wnn  = w & 1;           // 0..1: cols wnn*64

    const ulonglong2* Ab = Ap + (size_t)bx * KST * SLOTS;
    const ulonglong2* Bb = Bp + (size_t)by * KST * SLOTS;

    // stage k-step s into sBuf[bufIdx]: 16 wave-instrs/block, 4 per wave.
    auto STAGE = [&](int bufIdx, int s) {
        const ulonglong2* As = Ab + (size_t)s * SLOTS;
        const ulonglong2* Bs = Bb + (size_t)s * SLOTS;
        #pragma unroll
        for (int i = 0; i < 4; ++i) {
            const int g = w * 4 + i;                 // 0..15
            const int off = (g & 7) * 64;
            const ulonglong2* src = (g < 8) ? (As + off + lane) : (Bs + off + lane);
            ulonglong2* dst = &sBuf[bufIdx][(g < 8 ? 0 : 512) + off];
            gload_lds16(src, dst);
        }
    };

    f32x16 accT00, accT01, accT10, accT11;   // cols(lane&31)=logit rows
    #pragma unroll
    for (int i = 0; i < 16; ++i) { accT00[i] = 0.f; accT01[i] = 0.f; accT10[i] = 0.f; accT11[i] = 0.f; }

    STAGE(0, 0);
    STAGE(1, 1);
    asm volatile("s_waitcnt vmcnt(4)" ::: "memory");   // buf0's 4 (per wave) done
    __builtin_amdgcn_s_barrier();

    #pragma unroll
    for (int s = 0; s < KST; ++s) {
        const int cur = s & 1;
        const ulonglong2* Abuf = &sBuf[cur][0];
        const ulonglong2* Bbuf = &sBuf[cur][512];
        // fragment ds_reads (conflict-free: 1KB contiguous per wave-instr)
        const ulonglong2 ca0 = Abuf[((wm * 2 + 0) * 2 + 0) * 64 + lane];   // m0,k32=0
        const ulonglong2 ca1 = Abuf[((wm * 2 + 0) * 2 + 1) * 64 + lane];   // m0,k32=1
        const ulonglong2 ca2 = Abuf[((wm * 2 + 1) * 2 + 0) * 64 + lane];   // m1,k32=0
        const ulonglong2 ca3 = Abuf[((wm * 2 + 1) * 2 + 1) * 64 + lane];   // m1,k32=1
        const ulonglong2 cb0 = Bbuf[((wnn * 2 + 0) * 2 + 0) * 64 + lane];
        const ulonglong2 cb1 = Bbuf[((wnn * 2 + 0) * 2 + 1) * 64 + lane];
        const ulonglong2 cb2 = Bbuf[((wnn * 2 + 1) * 2 + 0) * 64 + lane];
        const ulonglong2 cb3 = Bbuf[((wnn * 2 + 1) * 2 + 1) * 64 + lane];
        __builtin_amdgcn_s_setprio(1);
        mfma_fp8_t(accT00, cb0.x, ca0.x);
        mfma_fp8_t(accT01, cb0.x, ca2.x);
        mfma_fp8_t(accT10, cb2.x, ca0.x);
        mfma_fp8_t(accT11, cb2.x, ca2.x);
        mfma_fp8_t(accT00, cb0.y, ca0.y);
        mfma_fp8_t(accT01, cb0.y, ca2.y);
        mfma_fp8_t(accT10, cb2.y, ca0.y);
        mfma_fp8_t(accT11, cb2.y, ca2.y);
        mfma_fp8_t(accT00, cb1.x, ca1.x);
        mfma_fp8_t(accT01, cb1.x, ca3.x);
        mfma_fp8_t(accT10, cb3.x, ca1.x);
        mfma_fp8_t(accT11, cb3.x, ca3.x);
        mfma_fp8_t(accT00, cb1.y, ca1.y);
        mfma_fp8_t(accT01, cb1.y, ca3.y);
        mfma_fp8_t(accT10, cb3.y, ca1.y);
        mfma_fp8_t(accT11, cb3.y, ca3.y);
        __builtin_amdgcn_s_setprio(0);
        __builtin_amdgcn_s_barrier();                  // barA: all done reading buf[cur]
        if (s + 2 < KST) STAGE(cur, s + 2);            // overwrite cur with s+2
        if (s + 1 < KST) {
            if (s + 2 < KST) {
                asm volatile("s_waitcnt vmcnt(4)" ::: "memory");   // s+1's stage done
            } else {
                asm volatile("s_waitcnt vmcnt(0)" ::: "memory");   // last: drain
            }
            __builtin_amdgcn_s_barrier();              // barB: everyone's s+1 visible
        }
    }

    // ---- epilogue: per-lane row partials, single cross-lane step ----
    float zA = 0.0f;   // row = wm*64 + l31
    float zB = 0.0f;   // row = wm*64 + 32 + l31
    const int cbase = by * BNt + wnn * 64 + 4 * half;
    #pragma unroll
    for (int r = 0; r < 16; ++r) {
        const int cb = cbase + (r & 3) + 8 * (r >> 2);
        const float eA0 = (cb      < C) ? __expf(fmaf(accT00[r], S_SCALE, -MFIX)) : 0.0f;
        const float eB0 = (cb      < C) ? __expf(fmaf(accT01[r], S_SCALE, -MFIX)) : 0.0f;
        const float eA1 = (cb + 32 < C) ? __expf(fmaf(accT10[r], S_SCALE, -MFIX)) : 0.0f;
        const float eB1 = (cb + 32 < C) ? __expf(fmaf(accT11[r], S_SCALE, -MFIX)) : 0.0f;
        zA += eA0 + eA1;
        zB += eB0 + eB1;
    }
    zA += __shfl_xor(zA, 32, 64);    // combine the two col-halves of each row
    zB += __shfl_xor(zB, 32, 64);
    if (half == 0) {
        sRed[wm * 64 + l31][wnn]      = zA;
        sRed[wm * 64 + 32 + l31][wnn] = zB;
    }
    __syncthreads();
    if (tid < BMt) {
        pZ[(size_t)(bx * BMt + tid) * NPAN + by] = sRed[tid][0] + sRed[tid][1];
    }
}

// One wave per row: sum NPAN partials (fixed shift M=30), exact fp32 target
// logits + ArcFace margin, correct Z, emit per-row loss.
__global__ void finalize_kernel(const float* __restrict__ f, const float* __restrict__ w,
                                const float* __restrict__ fn, const float* __restrict__ wn,
                                const int* __restrict__ pinds, const int* __restrict__ lengths,
                                const float* __restrict__ pZ, float* __restrict__ loss)
{
    const int b = blockIdx.x;
    const int lane = threadIdx.x;

    float Zp = 0.0f;
    for (int p = lane; p < NPAN; p += 64) Zp += pZ[(size_t)b * NPAN + p];
    Zp = wave_sum(Zp);

    const float4* fp = reinterpret_cast<const float4*>(f + (size_t)b * D);
    const float4 a0 = fp[lane * 2 + 0];
    const float4 a1 = fp[lane * 2 + 1];
    const float fnb = fn[b];
    const int len = lengths[b];

    float opl[LMAX], ops[LMAX];
    int cs[LMAX];
    #pragma unroll
    for (int j = 0; j < LMAX; ++j) {
        const int c = pinds[(size_t)b * LMAX + j];
        cs[j] = c;
        const float4* wp = reinterpret_cast<const float4*>(w + (size_t)c * D);
        const float4 w0 = wp[lane * 2 + 0];
        const float4 w1 = wp[lane * 2 + 1];
        float d = a0.x*w0.x + a0.y*w0.y + a0.z*w0.z + a0.w*w0.w
                + a1.x*w1.x + a1.y*w1.y + a1.z*w1.z + a1.w*w1.w;
        d = wave_sum(d);
        const float cosv = d / fmaxf(fnb * wn[c], 1e-8f);
        const float sine = sqrtf(fminf(fmaxf(1.0f - cosv * cosv, 0.0f), 1.0f));
        float phi = cosv * COS_M - sine * SIN_M;
        phi = (cosv > TH) ? phi : (cosv - MM);
        opl[j] = S_SCALE * cosv;
        ops[j] = S_SCALE * phi;
    }

    // correct Z for unique positive classes (margin applied), then ragged CE
    float Zc = Zp;
    for (int j = 0; j < len; ++j) {
        bool dup = false;
        for (int jj = 0; jj < j; ++jj) dup = dup || (cs[jj] == cs[j]);
        if (!dup) Zc += expf(ops[j] - MFIX) - expf(opl[j] - MFIX);
    }
    const float lZ = logf(Zc);
    float acc = 0.0f;
    for (int j = 0; j < len; ++j) acc += (MFIX + lZ - ops[j]);
    const float Lf = (float)len;
    if (lane == 0) loss[b] = acc / (Lf * Lf);
}

__global__ void reduce_kernel(const float* __restrict__ loss, float* __restrict__ out) {
    __shared__ float sdata[256];
    const int t = threadIdx.x;
    float s = 0.0f;
    for (int i = t; i < B; i += 256) s += loss[i];
    sdata[t] = s;
    __syncthreads();
    for (int off = 128; off > 0; off >>= 1) {
        if (t < off) sdata[t] += sdata[t + off];
        __syncthreads();
    }
    if (t == 0) out[0] = sdata[0] * (1.0f / (float)B);
}

} // anonymous namespace

extern "C" void kernel_launch(void* const* d_in, const int* in_sizes, int n_in,
                              void* d_out, int out_size, void* d_ws, size_t ws_size,
                              hipStream_t stream) {
    const float* f   = (const float*)d_in[0];
    // d_in[1] = labels [B,C] — not needed (reconstructed from pinds/lengths)
    const float* w   = (const float*)d_in[2];
    const int* pinds = (const int*)d_in[3];
    const int* lens  = (const int*)d_in[4];
    float* out = (float*)d_out;

    char* ws = (char*)d_ws;
    size_t off = 0;
    auto alloc = [&](size_t bytes) { void* p = ws + off; off = (off + bytes + 255) & ~(size_t)255; return p; };

    float* wn   = (float*)alloc(C * 4);
    float* winv = (float*)alloc(C * 4);
    float* fn   = (float*)alloc(B * 4);
    float* finv = (float*)alloc(B * 4);
    float* pZ   = (float*)alloc((size_t)B * NPAN * 4);
    float* loss = (float*)alloc(B * 4);
    ulonglong2* Ap = (ulonglong2*)alloc((size_t)NROWT * KST * SLOTS * 16);
    ulonglong2* Bp = (ulonglong2*)alloc((size_t)NPAN  * KST * SLOTS * 16);

    norm_kernel<<<dim3((B + C) / 4), 256, 0, stream>>>(f, w, fn, finv, wn, winv);
    pack_kernel<<<dim3(NPACK_A + NPACK_B), 256, 0, stream>>>(f, finv, w, winv, Ap, Bp);
    gemm_mfma_kernel<<<dim3(NWG), 256, 0, stream>>>(Ap, Bp, pZ);
    finalize_kernel<<<dim3(B), 64, 0, stream>>>(f, w, fn, wn, pinds, lens, pZ, loss);
    reduce_kernel<<<dim3(1), 256, 0, stream>>>(loss, out);
}

// Round 17
// 62.163 us; speedup vs baseline: 1.6732x; 1.1369x over previous
//
#include <hip/hip_runtime.h>
#include <math.h>

namespace {

constexpr int B = 2048;
constexpr int C = 20000;
constexpr int D = 512;
constexpr int LMAX = 8;

constexpr int BMt = 128, BNt = 128;          // GEMM block tile
constexpr int NROWT = B / BMt;               // 16 row tiles
constexpr int NPAN  = (C + BNt - 1) / BNt;   // 157 col panels (last: 32 valid)
constexpr int KST   = D / 64;                // 8 K-steps
constexpr int SLOTS = 512;                   // 16B slots per (tile,kstep)
constexpr int NWG   = NROWT * NPAN;          // 2512 (divisible by 8 XCDs)
constexpr int NPACK_A = NROWT * KST;         // 128 pack blocks for A
constexpr int NPACK_B = NPAN * KST;          // 1256 pack blocks for B

constexpr float S_SCALE = 30.0f;
constexpr float COS_M = 0.87758256189037271f;   // cos(0.5)
constexpr float SIN_M = 0.47942553860420301f;   // sin(0.5)
constexpr float TH    = -0.87758256189037271f;  // cos(pi - 0.5)
constexpr float MM    = 0.23971276930210156f;   // sin(pi - 0.5) * 0.5
constexpr float MFIX  = 30.0f;                  // fixed softmax shift: |logits| <= 30

typedef float f32x16 __attribute__((ext_vector_type(16)));
typedef int   i32x8  __attribute__((ext_vector_type(8)));

union FragU { ulonglong2 u2[2]; i32x8 v; };

// MX-scaled fp8 MFMA, K=64, unit scales (E8M0 127 -> 2^0). With identical
// k-permutations on both operands the result equals the plain dot product.
// Transposed: first operand = our B (cols) -> D cols (lane&31) = logit ROWS.
__device__ __forceinline__ void mfma_mx_t(f32x16& acc, i32x8 bfrag, i32x8 afrag) {
    acc = __builtin_amdgcn_mfma_scale_f32_32x32x64_f8f6f4(
        bfrag, afrag, acc, 0 /*cbsz: fp8*/, 0 /*blgp: fp8*/,
        0, 0x7F7F7F7F, 0, 0x7F7F7F7F);
}

// async global->LDS, 16B per lane; LDS dest = uniform base + lane*16 (HW).
__device__ __forceinline__ void gload_lds16(const ulonglong2* gsrc_lane, ulonglong2* lds_base) {
    __builtin_amdgcn_global_load_lds(
        (const __attribute__((address_space(1))) unsigned int*)gsrc_lane,
        (__attribute__((address_space(3))) unsigned int*)lds_base,
        16, 0, 0);
}

// 8 fp32 -> 8 fp8 e4m3 bytes (hardware RNE pack), element j = byte j
__device__ __forceinline__ unsigned long long pack8_fp8(const float* xs, float sc) {
    int d0 = __builtin_amdgcn_cvt_pk_fp8_f32(xs[0] * sc, xs[1] * sc, 0, false);
    d0 = __builtin_amdgcn_cvt_pk_fp8_f32(xs[2] * sc, xs[3] * sc, d0, true);
    int d1 = __builtin_amdgcn_cvt_pk_fp8_f32(xs[4] * sc, xs[5] * sc, 0, false);
    d1 = __builtin_amdgcn_cvt_pk_fp8_f32(xs[6] * sc, xs[7] * sc, d1, true);
    return (unsigned long long)(unsigned)d0 | ((unsigned long long)(unsigned)d1 << 32);
}

__device__ __forceinline__ float wave_sum(float v) {
    #pragma unroll
    for (int off = 1; off < 64; off <<= 1) v += __shfl_xor(v, off, 64);
    return v;
}

// Merged norm: one wave per row over BOTH f (rows 0..B) and w (rows B..B+C).
__global__ void norm_kernel(const float* __restrict__ f, const float* __restrict__ w,
                            float* __restrict__ fn, float* __restrict__ finv,
                            float* __restrict__ wn, float* __restrict__ winv) {
    const int wave = threadIdx.x >> 6, lane = threadIdx.x & 63;
    const int r = blockIdx.x * 4 + wave;
    const float* x;
    float *no, *io;
    int row;
    if (r < B) { x = f; row = r; no = fn; io = finv; }
    else       { x = w; row = r - B; no = wn; io = winv; if (row >= C) return; }
    const float4* p = reinterpret_cast<const float4*>(x + (size_t)row * D);
    const float4 a = p[lane * 2 + 0];
    const float4 b = p[lane * 2 + 1];
    float s = a.x*a.x + a.y*a.y + a.z*a.z + a.w*a.w
            + b.x*b.x + b.y*b.y + b.z*b.z + b.w*b.w;
    s = wave_sum(s);
    if (lane == 0) {
        const float nrm = sqrtf(s);
        no[row] = nrm;
        io[row] = 1.0f / fmaxf(nrm, 1e-8f);
    }
}

// Merged pack: blocks [0,128) pack A tiles, [128,1384) pack B panels.
// Pre-normalized fp8 e4m3. Slot u = q2*64 + l, q2 = m_frag*2 + k32; slot.x/.y
// = k16 pair: half h elems j: row = m_frag*32+(l&31), k = k32*32+h*16+(l>>5)*8+j.
__global__ void pack_kernel(const float* __restrict__ f, const float* __restrict__ finv,
                            const float* __restrict__ w, const float* __restrict__ winv,
                            ulonglong2* __restrict__ Ap, ulonglong2* __restrict__ Bp) {
    const int id = blockIdx.x;
    const bool isA = id < NPACK_A;
    const int bid = isA ? id : id - NPACK_A;
    const int tile = bid >> 3, s = bid & 7;
    const int rbase = tile * 128;
    const float* src = isA ? f : w;
    const float* inv = isA ? finv : winv;
    ulonglong2* blk = (isA ? Ap : Bp) + (size_t)bid * SLOTS;
    const int t = threadIdx.x;
    #pragma unroll
    for (int i = 0; i < 2; ++i) {
        const int v = i * 256 + t;           // slot 0..511
        const int q2 = v >> 6, l = v & 63;
        const int mfr = q2 >> 1, k32 = q2 & 1;
        const int row = rbase + mfr * 32 + (l & 31);
        ulonglong2 slot = make_ulonglong2(0ull, 0ull);
        if (isA || row < C) {
            const int kb = s * 64 + k32 * 32 + ((l >> 5) << 3);
            const float sc = inv[row];
            float xs[8];
            *reinterpret_cast<float4*>(&xs[0]) = *reinterpret_cast<const float4*>(&src[(size_t)row * D + kb]);
            *reinterpret_cast<float4*>(&xs[4]) = *reinterpret_cast<const float4*>(&src[(size_t)row * D + kb + 4]);
            slot.x = pack8_fp8(xs, sc);
            *reinterpret_cast<float4*>(&xs[0]) = *reinterpret_cast<const float4*>(&src[(size_t)row * D + kb + 16]);
            *reinterpret_cast<float4*>(&xs[4]) = *reinterpret_cast<const float4*>(&src[(size_t)row * D + kb + 20]);
            slot.y = pack8_fp8(xs, sc);
        }
        blk[v] = slot;
    }
}

// MX-FP8 MFMA GEMM with LDS double-buffer + counted vmcnt deep pipeline
// (T3/T4, proven R16): global_load_lds stages each k-step once per block,
// vmcnt never drained to 0 in the main loop, raw s_barrier. K=64 scaled
// MFMA: 4 per k-step per wave (was 16 x K=16) at 2x the FLOP rate.
// Transposed accumulate: lane&31 owns one logit ROW.
// pZ[row][panel] = sum_cols exp(30*cos - 30).
__global__ __launch_bounds__(256, 3) void
gemm_mfma_kernel(const ulonglong2* __restrict__ Ap, const ulonglong2* __restrict__ Bp,
                 float* __restrict__ pZ)
{
    __shared__ ulonglong2 sBuf[2][1024];   // [buf][A:0..511 | B:512..1023] = 32KB
    __shared__ float sRed[BMt][2];
    const int wgid = blockIdx.x;
    const int swz = (wgid & 7) * (NWG / 8) + (wgid >> 3);   // bijective (NWG%8==0)
    const int bx = swz & 15;          // row tile
    const int by = swz >> 4;          // panel
    const int tid  = threadIdx.x;
    const int lane = tid & 63;
    const int half = lane >> 5, l31 = lane & 31;
    const int w    = tid >> 6;
    const int wm   = w >> 1;          // 0..1: rows wm*64
    const int wnn  = w & 1;           // 0..1: cols wnn*64

    const ulonglong2* Ab = Ap + (size_t)bx * KST * SLOTS;
    const ulonglong2* Bb = Bp + (size_t)by * KST * SLOTS;

    // stage k-step s into sBuf[bufIdx]: 16 wave-instrs/block, 4 per wave.
    auto STAGE = [&](int bufIdx, int s) {
        const ulonglong2* As = Ab + (size_t)s * SLOTS;
        const ulonglong2* Bs = Bb + (size_t)s * SLOTS;
        #pragma unroll
        for (int i = 0; i < 4; ++i) {
            const int g = w * 4 + i;                 // 0..15
            const int off = (g & 7) * 64;
            const ulonglong2* src = (g < 8) ? (As + off + lane) : (Bs + off + lane);
            ulonglong2* dst = &sBuf[bufIdx][(g < 8 ? 0 : 512) + off];
            gload_lds16(src, dst);
        }
    };

    f32x16 accT00, accT01, accT10, accT11;   // cols(lane&31)=logit rows
    #pragma unroll
    for (int i = 0; i < 16; ++i) { accT00[i] = 0.f; accT01[i] = 0.f; accT10[i] = 0.f; accT11[i] = 0.f; }

    STAGE(0, 0);
    STAGE(1, 1);
    asm volatile("s_waitcnt vmcnt(4)" ::: "memory");   // buf0's 4 (per wave) done
    __builtin_amdgcn_s_barrier();

    #pragma unroll
    for (int s = 0; s < KST; ++s) {
        const int cur = s & 1;
        const ulonglong2* Abuf = &sBuf[cur][0];
        const ulonglong2* Bbuf = &sBuf[cur][512];
        // fragment ds_reads (conflict-free: 1KB contiguous per wave-instr);
        // assemble K=64 operands: {k32=0}.x,.y,{k32=1}.x,.y (same order for A
        // and B -> identical k-permutation -> dot product exact).
        FragU a0u, a1u, b0u, b1u;
        a0u.u2[0] = Abuf[((wm * 2 + 0) * 2 + 0) * 64 + lane];   // m0,k32=0
        a0u.u2[1] = Abuf[((wm * 2 + 0) * 2 + 1) * 64 + lane];   // m0,k32=1
        a1u.u2[0] = Abuf[((wm * 2 + 1) * 2 + 0) * 64 + lane];   // m1,k32=0
        a1u.u2[1] = Abuf[((wm * 2 + 1) * 2 + 1) * 64 + lane];   // m1,k32=1
        b0u.u2[0] = Bbuf[((wnn * 2 + 0) * 2 + 0) * 64 + lane];
        b0u.u2[1] = Bbuf[((wnn * 2 + 0) * 2 + 1) * 64 + lane];
        b1u.u2[0] = Bbuf[((wnn * 2 + 1) * 2 + 0) * 64 + lane];
        b1u.u2[1] = Bbuf[((wnn * 2 + 1) * 2 + 1) * 64 + lane];
        __builtin_amdgcn_s_setprio(1);
        mfma_mx_t(accT00, b0u.v, a0u.v);
        mfma_mx_t(accT01, b0u.v, a1u.v);
        mfma_mx_t(accT10, b1u.v, a0u.v);
        mfma_mx_t(accT11, b1u.v, a1u.v);
        __builtin_amdgcn_s_setprio(0);
        __builtin_amdgcn_s_barrier();                  // barA: all done reading buf[cur]
        if (s + 2 < KST) STAGE(cur, s + 2);            // overwrite cur with s+2
        if (s + 1 < KST) {
            if (s + 2 < KST) {
                asm volatile("s_waitcnt vmcnt(4)" ::: "memory");   // s+1's stage done
            } else {
                asm volatile("s_waitcnt vmcnt(0)" ::: "memory");   // last: drain
            }
            __builtin_amdgcn_s_barrier();              // barB: everyone's s+1 visible
        }
    }

    // ---- epilogue: per-lane row partials, single cross-lane step ----
    float zA = 0.0f;   // row = wm*64 + l31
    float zB = 0.0f;   // row = wm*64 + 32 + l31
    const int cbase = by * BNt + wnn * 64 + 4 * half;
    #pragma unroll
    for (int r = 0; r < 16; ++r) {
        const int cb = cbase + (r & 3) + 8 * (r >> 2);
        const float eA0 = (cb      < C) ? __expf(fmaf(accT00[r], S_SCALE, -MFIX)) : 0.0f;
        const float eB0 = (cb      < C) ? __expf(fmaf(accT01[r], S_SCALE, -MFIX)) : 0.0f;
        const float eA1 = (cb + 32 < C) ? __expf(fmaf(accT10[r], S_SCALE, -MFIX)) : 0.0f;
        const float eB1 = (cb + 32 < C) ? __expf(fmaf(accT11[r], S_SCALE, -MFIX)) : 0.0f;
        zA += eA0 + eA1;
        zB += eB0 + eB1;
    }
    zA += __shfl_xor(zA, 32, 64);    // combine the two col-halves of each row
    zB += __shfl_xor(zB, 32, 64);
    if (half == 0) {
        sRed[wm * 64 + l31][wnn]      = zA;
        sRed[wm * 64 + 32 + l31][wnn] = zB;
    }
    __syncthreads();
    if (tid < BMt) {
        pZ[(size_t)(bx * BMt + tid) * NPAN + by] = sRed[tid][0] + sRed[tid][1];
    }
}

// One wave per row: sum NPAN partials (fixed shift M=30), exact fp32 target
// logits + ArcFace margin, correct Z, emit per-row loss.
__global__ void finalize_kernel(const float* __restrict__ f, const float* __restrict__ w,
                                const float* __restrict__ fn, const float* __restrict__ wn,
                                const int* __restrict__ pinds, const int* __restrict__ lengths,
                                const float* __restrict__ pZ, float* __restrict__ loss)
{
    const int b = blockIdx.x;
    const int lane = threadIdx.x;

    float Zp = 0.0f;
    for (int p = lane; p < NPAN; p += 64) Zp += pZ[(size_t)b * NPAN + p];
    Zp = wave_sum(Zp);

    const float4* fp = reinterpret_cast<const float4*>(f + (size_t)b * D);
    const float4 a0 = fp[lane * 2 + 0];
    const float4 a1 = fp[lane * 2 + 1];
    const float fnb = fn[b];
    const int len = lengths[b];

    float opl[LMAX], ops[LMAX];
    int cs[LMAX];
    #pragma unroll
    for (int j = 0; j < LMAX; ++j) {
        const int c = pinds[(size_t)b * LMAX + j];
        cs[j] = c;
        const float4* wp = reinterpret_cast<const float4*>(w + (size_t)c * D);
        const float4 w0 = wp[lane * 2 + 0];
        const float4 w1 = wp[lane * 2 + 1];
        float d = a0.x*w0.x + a0.y*w0.y + a0.z*w0.z + a0.w*w0.w
                + a1.x*w1.x + a1.y*w1.y + a1.z*w1.z + a1.w*w1.w;
        d = wave_sum(d);
        const float cosv = d / fmaxf(fnb * wn[c], 1e-8f);
        const float sine = sqrtf(fminf(fmaxf(1.0f - cosv * cosv, 0.0f), 1.0f));
        float phi = cosv * COS_M - sine * SIN_M;
        phi = (cosv > TH) ? phi : (cosv - MM);
        opl[j] = S_SCALE * cosv;
        ops[j] = S_SCALE * phi;
    }

    // correct Z for unique positive classes (margin applied), then ragged CE
    float Zc = Zp;
    for (int j = 0; j < len; ++j) {
        bool dup = false;
        for (int jj = 0; jj < j; ++jj) dup = dup || (cs[jj] == cs[j]);
        if (!dup) Zc += expf(ops[j] - MFIX) - expf(opl[j] - MFIX);
    }
    const float lZ = logf(Zc);
    float acc = 0.0f;
    for (int j = 0; j < len; ++j) acc += (MFIX + lZ - ops[j]);
    const float Lf = (float)len;
    if (lane == 0) loss[b] = acc / (Lf * Lf);
}

__global__ void reduce_kernel(const float* __restrict__ loss, float* __restrict__ out) {
    __shared__ float sdata[256];
    const int t = threadIdx.x;
    float s = 0.0f;
    for (int i = t; i < B; i += 256) s += loss[i];
    sdata[t] = s;
    __syncthreads();
    for (int off = 128; off > 0; off >>= 1) {
        if (t < off) sdata[t] += sdata[t + off];
        __syncthreads();
    }
    if (t == 0) out[0] = sdata[0] * (1.0f / (float)B);
}

} // anonymous namespace

extern "C" void kernel_launch(void* const* d_in, const int* in_sizes, int n_in,
                              void* d_out, int out_size, void* d_ws, size_t ws_size,
                              hipStream_t stream) {
    const float* f   = (const float*)d_in[0];
    // d_in[1] = labels [B,C] — not needed (reconstructed from pinds/lengths)
    const float* w   = (const float*)d_in[2];
    const int* pinds = (const int*)d_in[3];
    const int* lens  = (const int*)d_in[4];
    float* out = (float*)d_out;

    char* ws = (char*)d_ws;
    size_t off = 0;
    auto alloc = [&](size_t bytes) { void* p = ws + off; off = (off + bytes + 255) & ~(size_t)255; return p; };

    float* wn   = (float*)alloc(C * 4);
    float* winv = (float*)alloc(C * 4);
    float* fn   = (float*)alloc(B * 4);
    float* finv = (float*)alloc(B * 4);
    float* pZ   = (float*)alloc((size_t)B * NPAN * 4);
    float* loss = (float*)alloc(B * 4);
    ulonglong2* Ap = (ulonglong2*)alloc((size_t)NROWT * KST * SLOTS * 16);
    ulonglong2* Bp = (ulonglong2*)alloc((size_t)NPAN  * KST * SLOTS * 16);

    norm_kernel<<<dim3((B + C) / 4), 256, 0, stream>>>(f, w, fn, finv, wn, winv);
    pack_kernel<<<dim3(NPACK_A + NPACK_B), 256, 0, stream>>>(f, finv, w, winv, Ap, Bp);
    gemm_mfma_kernel<<<dim3(NWG), 256, 0, stream>>>(Ap, Bp, pZ);
    finalize_kernel<<<dim3(B), 64, 0, stream>>>(f, w, fn, wn, pinds, lens, pZ, loss);
    reduce_kernel<<<dim3(1), 256, 0, stream>>>(loss, out);
}

// Round 18
// 60.084 us; speedup vs baseline: 1.7311x; 1.0346x over previous
//
#include <hip/hip_runtime.h>
#include <math.h>

namespace {

constexpr int B = 2048;
constexpr int C = 20000;
constexpr int D = 512;
constexpr int LMAX = 8;

constexpr int BMt = 128, BNt = 128;          // GEMM block tile
constexpr int NROWT = B / BMt;               // 16 row tiles
constexpr int NPAN  = (C + BNt - 1) / BNt;   // 157 col panels (last: 32 valid)
constexpr int KST   = D / 64;                // 8 K-steps
constexpr int SLOTS = 512;                   // 16B slots per (tile,kstep)
constexpr int NWG   = NROWT * NPAN;          // 2512 (divisible by 8 XCDs)
constexpr int NBLK_F = B / 32;               // 64 fused norm+pack blocks for f
constexpr int NBLK_W = C / 32;               // 625 for w
constexpr int NBLK_PAD = 3;                  // zero-fill pad rows 20000..20095

constexpr float S_SCALE = 30.0f;
constexpr float COS_M = 0.87758256189037271f;   // cos(0.5)
constexpr float SIN_M = 0.47942553860420301f;   // sin(0.5)
constexpr float TH    = -0.87758256189037271f;  // cos(pi - 0.5)
constexpr float MM    = 0.23971276930210156f;   // sin(pi - 0.5) * 0.5
constexpr float MFIX  = 30.0f;                  // fixed softmax shift: |logits| <= 30

typedef float f32x16 __attribute__((ext_vector_type(16)));
typedef int   i32x8  __attribute__((ext_vector_type(8)));

union FragU { ulonglong2 u2[2]; i32x8 v; };

// MX-scaled fp8 MFMA, K=64, unit scales (E8M0 127 -> 2^0). With identical
// k-permutations on both operands the result equals the plain dot product.
// Transposed: first operand = our B (cols) -> D cols (lane&31) = logit ROWS.
__device__ __forceinline__ void mfma_mx_t(f32x16& acc, i32x8 bfrag, i32x8 afrag) {
    acc = __builtin_amdgcn_mfma_scale_f32_32x32x64_f8f6f4(
        bfrag, afrag, acc, 0 /*cbsz: fp8*/, 0 /*blgp: fp8*/,
        0, 0x7F7F7F7F, 0, 0x7F7F7F7F);
}

// async global->LDS, 16B per lane; LDS dest = uniform base + lane*16 (HW).
__device__ __forceinline__ void gload_lds16(const ulonglong2* gsrc_lane, ulonglong2* lds_base) {
    __builtin_amdgcn_global_load_lds(
        (const __attribute__((address_space(1))) unsigned int*)gsrc_lane,
        (__attribute__((address_space(3))) unsigned int*)lds_base,
        16, 0, 0);
}

// 8 fp32 -> 8 fp8 e4m3 bytes (hardware RNE pack), element j = byte j
__device__ __forceinline__ unsigned long long pack8_fp8(const float* xs, float sc) {
    int d0 = __builtin_amdgcn_cvt_pk_fp8_f32(xs[0] * sc, xs[1] * sc, 0, false);
    d0 = __builtin_amdgcn_cvt_pk_fp8_f32(xs[2] * sc, xs[3] * sc, d0, true);
    int d1 = __builtin_amdgcn_cvt_pk_fp8_f32(xs[4] * sc, xs[5] * sc, 0, false);
    d1 = __builtin_amdgcn_cvt_pk_fp8_f32(xs[6] * sc, xs[7] * sc, d1, true);
    return (unsigned long long)(unsigned)d0 | ((unsigned long long)(unsigned)d1 << 32);
}

__device__ __forceinline__ float wave_sum(float v) {
    #pragma unroll
    for (int off = 1; off < 64; off <<= 1) v += __shfl_xor(v, off, 64);
    return v;
}

// Fused norm+pack: one block = 32 rows = one m_frag slot-group.
// Phase 1: coalesced per-wave-per-row norms (8 rows/wave), store 1/nrm in LDS.
// Phase 2: pack all 8 k-steps; source rows are L2-hot (same XCD, just read).
// Blocks [0,64): f tiles. [64,689): w panels. [689,692): zero pad rows
// 20000..20095 of the last panel (slots otherwise hold harness poison).
// Slot u = q2*64 + l, q2 = mfr*2 + k32; slot.x/.y = k16 pair: half h elems j:
// row = mfr*32+(l&31), k = k32*32 + h*16 + (l>>5)*8 + j.
__global__ void pack_norm_kernel(const float* __restrict__ f, const float* __restrict__ w,
                                 float* __restrict__ fn, float* __restrict__ wn,
                                 ulonglong2* __restrict__ Ap, ulonglong2* __restrict__ Bp) {
    __shared__ float sInv[32];
    const int id = blockIdx.x;
    const int t = threadIdx.x, lane = t & 63, wv = t >> 6;

    if (id >= NBLK_F + NBLK_W) {                // pad-zero blocks
        const int g = id - (NBLK_F + NBLK_W);   // 0..2 -> mfr 1..3 of tile 156
        #pragma unroll
        for (int i = 0; i < 4; ++i) {
            const int v = i * 256 + t;          // 0..1023
            const int s = v >> 7, u = v & 127;
            const int k32 = u >> 6, l = u & 63;
            Bp[(size_t)((NPAN - 1) * KST + s) * SLOTS + ((g + 1) * 2 + k32) * 64 + l]
                = make_ulonglong2(0ull, 0ull);
        }
        return;
    }

    const bool isA = id < NBLK_F;
    const int r0 = (isA ? id : id - NBLK_F) * 32;       // first row of group
    const float* src = isA ? f : w;
    float* nrm_out = isA ? fn : wn;
    const int tile = r0 >> 7;                  // /128
    const int mfr = (r0 >> 5) & 3;             // (r0%128)/32
    ulonglong2* base = (isA ? Ap : Bp) + (size_t)(tile * KST) * SLOTS;

    // phase 1: wave wv handles rows wv*8 .. wv*8+7 (one row at a time, coalesced)
    #pragma unroll
    for (int rr = 0; rr < 8; ++rr) {
        const int lr = wv * 8 + rr;
        const int row = r0 + lr;
        const float4* p = reinterpret_cast<const float4*>(src + (size_t)row * D);
        const float4 a = p[lane * 2 + 0];
        const float4 b = p[lane * 2 + 1];
        float s2 = a.x*a.x + a.y*a.y + a.z*a.z + a.w*a.w
                 + b.x*b.x + b.y*b.y + b.z*b.z + b.w*b.w;
        s2 = wave_sum(s2);
        if (lane == 0) {
            const float nrm = sqrtf(s2);
            nrm_out[row] = nrm;
            sInv[lr] = 1.0f / fmaxf(nrm, 1e-8f);
        }
    }
    __syncthreads();

    // phase 2: pack 1024 slots (8 k-steps x 2 k32 x 64 lanes), 4 per thread
    #pragma unroll
    for (int i = 0; i < 4; ++i) {
        const int v = i * 256 + t;             // 0..1023
        const int s = v >> 7, u = v & 127;
        const int k32 = u >> 6, l = u & 63;
        const int lr = l & 31;
        const int row = r0 + lr;
        const int kb = s * 64 + k32 * 32 + ((l >> 5) << 3);
        const float sc = sInv[lr];
        float xs[8];
        *reinterpret_cast<float4*>(&xs[0]) = *reinterpret_cast<const float4*>(&src[(size_t)row * D + kb]);
        *reinterpret_cast<float4*>(&xs[4]) = *reinterpret_cast<const float4*>(&src[(size_t)row * D + kb + 4]);
        const unsigned long long lo = pack8_fp8(xs, sc);
        *reinterpret_cast<float4*>(&xs[0]) = *reinterpret_cast<const float4*>(&src[(size_t)row * D + kb + 16]);
        *reinterpret_cast<float4*>(&xs[4]) = *reinterpret_cast<const float4*>(&src[(size_t)row * D + kb + 20]);
        const unsigned long long hi = pack8_fp8(xs, sc);
        base[(size_t)s * SLOTS + (mfr * 2 + k32) * 64 + l] = make_ulonglong2(lo, hi);
    }
}

// MX-FP8 MFMA GEMM with LDS double-buffer + counted vmcnt deep pipeline
// (T3/T4, proven R16/R17). Transposed accumulate: lane&31 owns one logit ROW.
// pZ[row][panel] = sum_cols exp(30*cos - 30).
__global__ __launch_bounds__(256, 3) void
gemm_mfma_kernel(const ulonglong2* __restrict__ Ap, const ulonglong2* __restrict__ Bp,
                 float* __restrict__ pZ)
{
    __shared__ ulonglong2 sBuf[2][1024];   // [buf][A:0..511 | B:512..1023] = 32KB
    __shared__ float sRed[BMt][2];
    const int wgid = blockIdx.x;
    const int swz = (wgid & 7) * (NWG / 8) + (wgid >> 3);   // bijective (NWG%8==0)
    const int bx = swz & 15;          // row tile
    const int by = swz >> 4;          // panel
    const int tid  = threadIdx.x;
    const int lane = tid & 63;
    const int half = lane >> 5, l31 = lane & 31;
    const int w    = tid >> 6;
    const int wm   = w >> 1;          // 0..1: rows wm*64
    const int wnn  = w & 1;           // 0..1: cols wnn*64

    const ulonglong2* Ab = Ap + (size_t)bx * KST * SLOTS;
    const ulonglong2* Bb = Bp + (size_t)by * KST * SLOTS;

    auto STAGE = [&](int bufIdx, int s) {
        const ulonglong2* As = Ab + (size_t)s * SLOTS;
        const ulonglong2* Bs = Bb + (size_t)s * SLOTS;
        #pragma unroll
        for (int i = 0; i < 4; ++i) {
            const int g = w * 4 + i;                 // 0..15
            const int off = (g & 7) * 64;
            const ulonglong2* src = (g < 8) ? (As + off + lane) : (Bs + off + lane);
            ulonglong2* dst = &sBuf[bufIdx][(g < 8 ? 0 : 512) + off];
            gload_lds16(src, dst);
        }
    };

    f32x16 accT00, accT01, accT10, accT11;   // cols(lane&31)=logit rows
    #pragma unroll
    for (int i = 0; i < 16; ++i) { accT00[i] = 0.f; accT01[i] = 0.f; accT10[i] = 0.f; accT11[i] = 0.f; }

    STAGE(0, 0);
    STAGE(1, 1);
    asm volatile("s_waitcnt vmcnt(4)" ::: "memory");   // buf0's 4 (per wave) done
    __builtin_amdgcn_s_barrier();

    #pragma unroll
    for (int s = 0; s < KST; ++s) {
        const int cur = s & 1;
        const ulonglong2* Abuf = &sBuf[cur][0];
        const ulonglong2* Bbuf = &sBuf[cur][512];
        FragU a0u, a1u, b0u, b1u;
        a0u.u2[0] = Abuf[((wm * 2 + 0) * 2 + 0) * 64 + lane];   // m0,k32=0
        a0u.u2[1] = Abuf[((wm * 2 + 0) * 2 + 1) * 64 + lane];   // m0,k32=1
        a1u.u2[0] = Abuf[((wm * 2 + 1) * 2 + 0) * 64 + lane];   // m1,k32=0
        a1u.u2[1] = Abuf[((wm * 2 + 1) * 2 + 1) * 64 + lane];   // m1,k32=1
        b0u.u2[0] = Bbuf[((wnn * 2 + 0) * 2 + 0) * 64 + lane];
        b0u.u2[1] = Bbuf[((wnn * 2 + 0) * 2 + 1) * 64 + lane];
        b1u.u2[0] = Bbuf[((wnn * 2 + 1) * 2 + 0) * 64 + lane];
        b1u.u2[1] = Bbuf[((wnn * 2 + 1) * 2 + 1) * 64 + lane];
        __builtin_amdgcn_s_setprio(1);
        mfma_mx_t(accT00, b0u.v, a0u.v);
        mfma_mx_t(accT01, b0u.v, a1u.v);
        mfma_mx_t(accT10, b1u.v, a0u.v);
        mfma_mx_t(accT11, b1u.v, a1u.v);
        __builtin_amdgcn_s_setprio(0);
        __builtin_amdgcn_s_barrier();                  // barA: all done reading buf[cur]
        if (s + 2 < KST) STAGE(cur, s + 2);            // overwrite cur with s+2
        if (s + 1 < KST) {
            if (s + 2 < KST) {
                asm volatile("s_waitcnt vmcnt(4)" ::: "memory");   // s+1's stage done
            } else {
                asm volatile("s_waitcnt vmcnt(0)" ::: "memory");   // last: drain
            }
            __builtin_amdgcn_s_barrier();              // barB: everyone's s+1 visible
        }
    }

    // ---- epilogue: per-lane row partials, single cross-lane step ----
    float zA = 0.0f;   // row = wm*64 + l31
    float zB = 0.0f;   // row = wm*64 + 32 + l31
    const int cbase = by * BNt + wnn * 64 + 4 * half;
    #pragma unroll
    for (int r = 0; r < 16; ++r) {
        const int cb = cbase + (r & 3) + 8 * (r >> 2);
        const float eA0 = (cb      < C) ? __expf(fmaf(accT00[r], S_SCALE, -MFIX)) : 0.0f;
        const float eB0 = (cb      < C) ? __expf(fmaf(accT01[r], S_SCALE, -MFIX)) : 0.0f;
        const float eA1 = (cb + 32 < C) ? __expf(fmaf(accT10[r], S_SCALE, -MFIX)) : 0.0f;
        const float eB1 = (cb + 32 < C) ? __expf(fmaf(accT11[r], S_SCALE, -MFIX)) : 0.0f;
        zA += eA0 + eA1;
        zB += eB0 + eB1;
    }
    zA += __shfl_xor(zA, 32, 64);    // combine the two col-halves of each row
    zB += __shfl_xor(zB, 32, 64);
    if (half == 0) {
        sRed[wm * 64 + l31][wnn]      = zA;
        sRed[wm * 64 + 32 + l31][wnn] = zB;
    }
    __syncthreads();
    if (tid < BMt) {
        pZ[(size_t)(bx * BMt + tid) * NPAN + by] = sRed[tid][0] + sRed[tid][1];
    }
}

// One wave per row: sum NPAN partials (fixed shift M=30), exact fp32 target
// logits + ArcFace margin, correct Z, emit per-row loss.
__global__ void finalize_kernel(const float* __restrict__ f, const float* __restrict__ w,
                                const float* __restrict__ fn, const float* __restrict__ wn,
                                const int* __restrict__ pinds, const int* __restrict__ lengths,
                                const float* __restrict__ pZ, float* __restrict__ loss)
{
    const int b = blockIdx.x;
    const int lane = threadIdx.x;

    float Zp = 0.0f;
    for (int p = lane; p < NPAN; p += 64) Zp += pZ[(size_t)b * NPAN + p];
    Zp = wave_sum(Zp);

    const float4* fp = reinterpret_cast<const float4*>(f + (size_t)b * D);
    const float4 a0 = fp[lane * 2 + 0];
    const float4 a1 = fp[lane * 2 + 1];
    const float fnb = fn[b];
    const int len = lengths[b];

    float opl[LMAX], ops[LMAX];
    int cs[LMAX];
    #pragma unroll
    for (int j = 0; j < LMAX; ++j) {
        const int c = pinds[(size_t)b * LMAX + j];
        cs[j] = c;
        const float4* wp = reinterpret_cast<const float4*>(w + (size_t)c * D);
        const float4 w0 = wp[lane * 2 + 0];
        const float4 w1 = wp[lane * 2 + 1];
        float d = a0.x*w0.x + a0.y*w0.y + a0.z*w0.z + a0.w*w0.w
                + a1.x*w1.x + a1.y*w1.y + a1.z*w1.z + a1.w*w1.w;
        d = wave_sum(d);
        const float cosv = d / fmaxf(fnb * wn[c], 1e-8f);
        const float sine = sqrtf(fminf(fmaxf(1.0f - cosv * cosv, 0.0f), 1.0f));
        float phi = cosv * COS_M - sine * SIN_M;
        phi = (cosv > TH) ? phi : (cosv - MM);
        opl[j] = S_SCALE * cosv;
        ops[j] = S_SCALE * phi;
    }

    // correct Z for unique positive classes (margin applied), then ragged CE
    float Zc = Zp;
    for (int j = 0; j < len; ++j) {
        bool dup = false;
        for (int jj = 0; jj < j; ++jj) dup = dup || (cs[jj] == cs[j]);
        if (!dup) Zc += expf(ops[j] - MFIX) - expf(opl[j] - MFIX);
    }
    const float lZ = logf(Zc);
    float acc = 0.0f;
    for (int j = 0; j < len; ++j) acc += (MFIX + lZ - ops[j]);
    const float Lf = (float)len;
    if (lane == 0) loss[b] = acc / (Lf * Lf);
}

__global__ void reduce_kernel(const float* __restrict__ loss, float* __restrict__ out) {
    __shared__ float sdata[256];
    const int t = threadIdx.x;
    float s = 0.0f;
    for (int i = t; i < B; i += 256) s += loss[i];
    sdata[t] = s;
    __syncthreads();
    for (int off = 128; off > 0; off >>= 1) {
        if (t < off) sdata[t] += sdata[t + off];
        __syncthreads();
    }
    if (t == 0) out[0] = sdata[0] * (1.0f / (float)B);
}

} // anonymous namespace

extern "C" void kernel_launch(void* const* d_in, const int* in_sizes, int n_in,
                              void* d_out, int out_size, void* d_ws, size_t ws_size,
                              hipStream_t stream) {
    const float* f   = (const float*)d_in[0];
    // d_in[1] = labels [B,C] — not needed (reconstructed from pinds/lengths)
    const float* w   = (const float*)d_in[2];
    const int* pinds = (const int*)d_in[3];
    const int* lens  = (const int*)d_in[4];
    float* out = (float*)d_out;

    char* ws = (char*)d_ws;
    size_t off = 0;
    auto alloc = [&](size_t bytes) { void* p = ws + off; off = (off + bytes + 255) & ~(size_t)255; return p; };

    float* wn   = (float*)alloc(C * 4);
    float* fn   = (float*)alloc(B * 4);
    float* pZ   = (float*)alloc((size_t)B * NPAN * 4);
    float* loss = (float*)alloc(B * 4);
    ulonglong2* Ap = (ulonglong2*)alloc((size_t)NROWT * KST * SLOTS * 16);
    ulonglong2* Bp = (ulonglong2*)alloc((size_t)NPAN  * KST * SLOTS * 16);

    pack_norm_kernel<<<dim3(NBLK_F + NBLK_W + NBLK_PAD), 256, 0, stream>>>(f, w, fn, wn, Ap, Bp);
    gemm_mfma_kernel<<<dim3(NWG), 256, 0, stream>>>(Ap, Bp, pZ);
    finalize_kernel<<<dim3(B), 64, 0, stream>>>(f, w, fn, wn, pinds, lens, pZ, loss);
    reduce_kernel<<<dim3(1), 256, 0, stream>>>(loss, out);
}